// Round 5
// baseline (132.011 us; speedup 1.0000x reference)
//
#include <hip/hip_runtime.h>

#define N 1024
#define NUM_IN 2048
#define NE (N * N)              // 1048576 elements of W_rec
#define TAU 20.0f
#define LR 0.001f
#define CHUNKS 64
#define RPC 48                  // rows per chunk: 64*48 = 3072 reduction rows

typedef float f4 __attribute__((ext_vector_type(4)));

// ---------------- Stage 1: partial sums of total_current --------------------
// Branch-free: every row is loaded and multiplied by its (mostly-zero) spike
// value. No per-row branch -> loads pipeline freely; 4 accumulators break the
// FMA dependence chain. 12 MB read at BW ~= 2 us.
__global__ __launch_bounds__(256) void lif_partial(
    const float* __restrict__ in_spk, const float* __restrict__ prev_spk,
    const float* __restrict__ W_in, const float* __restrict__ W_rec,
    float* __restrict__ partial) {
    __shared__ float spk[RPC];
    int jg = blockIdx.x & 3;
    int ic = blockIdx.x >> 2;
    int j = jg * 256 + threadIdx.x;
    int r0 = ic * RPC;
    if (threadIdx.x < RPC) {
        int r = r0 + threadIdx.x;
        spk[threadIdx.x] = (r < NUM_IN) ? in_spk[r] : prev_spk[r - NUM_IN];
    }
    __syncthreads();
    float acc0 = 0.f, acc1 = 0.f, acc2 = 0.f, acc3 = 0.f;
    #pragma unroll 8
    for (int u = 0; u < RPC; ++u) {
        int r = r0 + u;
        const float* Wrow = (r < NUM_IN) ? (W_in + (size_t)r * N)
                                         : (W_rec + (size_t)(r - NUM_IN) * N);
        float wv = Wrow[j];                      // unconditional, pipelines
        float s = spk[u];
        switch (u & 3) {
            case 0: acc0 = fmaf(s, wv, acc0); break;
            case 1: acc1 = fmaf(s, wv, acc1); break;
            case 2: acc2 = fmaf(s, wv, acc2); break;
            default: acc3 = fmaf(s, wv, acc3); break;
        }
    }
    partial[ic * N + j] = (acc0 + acc1) + (acc2 + acc3);
}

// ---------------- Stage 2: finish LIF + h = relu(combined @ pW1^T + pb1) ----
__global__ __launch_bounds__(256) void finish_mlp1(
    const float* __restrict__ partial, const float* __restrict__ potential,
    const float* __restrict__ prev_spk, const float* __restrict__ pW1,
    const float* __restrict__ pb1, float* __restrict__ out_spk,
    float* __restrict__ h) {
    __shared__ float comb[2 * N];
    __shared__ float red[256];
    int t = threadIdx.x;
    #pragma unroll
    for (int n0 = 0; n0 < N; n0 += 256) {
        int j = n0 + t;
        float tc = 0.f;
        #pragma unroll 8
        for (int ic = 0; ic < CHUNKS; ++ic) tc += partial[ic * N + j];
        float p = potential[j];
        float v = p + (-p / TAU + tc);           // DT = 1
        float s = (v >= 1.0f) ? 1.f : 0.f;
        comb[j] = prev_spk[j];
        comb[N + j] = s;
        if (blockIdx.x == 0) out_spk[j] = s;
    }
    __syncthreads();
    const float* row = pW1 + (size_t)blockIdx.x * (2 * N);
    float acc = 0.f;
    #pragma unroll
    for (int u = 0; u < 8; ++u) {
        int j = u * 256 + t;
        acc = fmaf(comb[j], row[j], acc);
    }
    red[t] = acc;
    __syncthreads();
    for (int s = 128; s > 0; s >>= 1) {
        if (t < s) red[t] += red[t + s];
        __syncthreads();
    }
    if (t == 0) h[blockIdx.x] = fmaxf(red[0] + pb1[blockIdx.x], 0.f);
}

// ---------------- Stage 3: fused policy GEMV + sigmoid + plasticity ---------
// 16 lanes per output element; wave covers 4 consecutive elements -> two
// contiguous 1KiB reads per iteration (plain loads: nt A/B'd out this round).
// 2-deep software pipeline, peeled epilogue, branch-free steady loop.
#define ITERS 32
#define ESTRIDE (8192 * 4)                       // elements advanced per iter
__global__ __launch_bounds__(256) void policy_update(
    const float* __restrict__ pW2, const float* __restrict__ pb2,
    const float* __restrict__ W_rec, const float* __restrict__ h,
    float* __restrict__ out_rec) {
    int lane = threadIdx.x & 63;
    int wave = threadIdx.x >> 6;
    int group = lane >> 4;
    int sub = lane & 15;
    int gw = blockIdx.x * 4 + wave;              // global wave id, 8192 total
    f4 hv = ((const f4*)h)[sub];                 // h[4*sub .. 4*sub+3]
    int e0 = gw * 4 + group;                     // this group's first element
    const f4* pr = (const f4*)(pW2 + (size_t)e0 * 64) + sub;
    const f4* gr = (const f4*)(pW2 + ((size_t)NE + e0) * 64) + sub;
    const size_t FSTRIDE = (size_t)ESTRIDE * 16; // f4 stride per iteration

    // prologue: load iteration 0 (pb2/W_rec loads unconditional: broadcast
    // within the 16-lane group, no exec-mask juggling)
    f4 a = *pr;
    f4 b = *gr;
    float bp = pb2[e0], bg = pb2[NE + e0], w = W_rec[e0];

    for (int it = 0; it < ITERS - 1; ++it) {
        // issue NEXT iteration's loads first (stay in flight during compute)
        const f4* prn = pr + (size_t)(it + 1) * FSTRIDE;
        const f4* grn = gr + (size_t)(it + 1) * FSTRIDE;
        f4 an = *prn;
        f4 bn = *grn;
        int en = e0 + (it + 1) * ESTRIDE;
        float bpn = pb2[en], bgn = pb2[NE + en], wn = W_rec[en];
        // compute current iteration
        float sp = a.x * hv.x + a.y * hv.y + a.z * hv.z + a.w * hv.w;
        float sg = b.x * hv.x + b.y * hv.y + b.z * hv.z + b.w * hv.w;
        #pragma unroll
        for (int off = 1; off < 16; off <<= 1) {
            sp += __shfl_xor(sp, off);
            sg += __shfl_xor(sg, off);
        }
        if (sub == 0) {
            int e = e0 + it * ESTRIDE;
            float sig_p = 1.f / (1.f + __expf(-(sp + bp)));
            float sig_g = 1.f / (1.f + __expf(-(sg + bg)));
            float nw = fmaxf(w - LR * sig_p + LR * sig_g, 0.f);
            int r = e >> 10, c = e & (N - 1);
            if (r == c) nw = 0.f;
            out_rec[e] = nw;
        }
        a = an; b = bn; bp = bpn; bg = bgn; w = wn;
    }
    {   // epilogue: last iteration
        float sp = a.x * hv.x + a.y * hv.y + a.z * hv.z + a.w * hv.w;
        float sg = b.x * hv.x + b.y * hv.y + b.z * hv.z + b.w * hv.w;
        #pragma unroll
        for (int off = 1; off < 16; off <<= 1) {
            sp += __shfl_xor(sp, off);
            sg += __shfl_xor(sg, off);
        }
        if (sub == 0) {
            int e = e0 + (ITERS - 1) * ESTRIDE;
            float sig_p = 1.f / (1.f + __expf(-(sp + bp)));
            float sig_g = 1.f / (1.f + __expf(-(sg + bg)));
            float nw = fmaxf(w - LR * sig_p + LR * sig_g, 0.f);
            int r = e >> 10, c = e & (N - 1);
            if (r == c) nw = 0.f;
            out_rec[e] = nw;
        }
    }
}

extern "C" void kernel_launch(void* const* d_in, const int* in_sizes, int n_in,
                              void* d_out, int out_size, void* d_ws, size_t ws_size,
                              hipStream_t stream) {
    const float* in_spk    = (const float*)d_in[0];
    const float* prev_spk  = (const float*)d_in[1];
    const float* potential = (const float*)d_in[2];
    const float* W_in      = (const float*)d_in[3];
    const float* W_rec     = (const float*)d_in[4];
    const float* pW1       = (const float*)d_in[5];
    const float* pb1       = (const float*)d_in[6];
    const float* pW2       = (const float*)d_in[7];
    const float* pb2       = (const float*)d_in[8];
    float* out = (float*)d_out;                  // [0,1024): spikes, then W_rec
    float* ws  = (float*)d_ws;
    float* partial = ws;                         // 64*1024 floats
    float* h       = ws + CHUNKS * N;            // 64 floats (16B-aligned)

    lif_partial<<<256, 256, 0, stream>>>(in_spk, prev_spk, W_in, W_rec, partial);
    finish_mlp1<<<64, 256, 0, stream>>>(partial, potential, prev_spk, pW1, pb1, out, h);
    policy_update<<<2048, 256, 0, stream>>>(pW2, pb2, W_rec, h, out + N);
}

// Round 6
// 115.746 us; speedup vs baseline: 1.1405x; 1.1405x over previous
//
#include <hip/hip_runtime.h>

#define N 1024
#define NUM_IN 2048
#define NE (N * N)              // 1048576 elements of W_rec
#define TAU 20.0f
#define LR 0.001f
#define CHUNKS 64
#define RPC 48                  // rows per chunk: 64*48 = 3072 reduction rows

typedef float f4 __attribute__((ext_vector_type(4)));

// ---------------- Stage 1: partial sums of total_current --------------------
// (round-3 version: wave-uniform skip branch, ~2.4 MB effective traffic)
__global__ __launch_bounds__(256) void lif_partial(
    const float* __restrict__ in_spk, const float* __restrict__ prev_spk,
    const float* __restrict__ W_in, const float* __restrict__ W_rec,
    float* __restrict__ partial) {
    __shared__ float spk[RPC];
    int jg = blockIdx.x & 3;
    int ic = blockIdx.x >> 2;
    int j = jg * 256 + threadIdx.x;
    int r0 = ic * RPC;
    if (threadIdx.x < RPC) {
        int r = r0 + threadIdx.x;
        spk[threadIdx.x] = (r < NUM_IN) ? in_spk[r] : prev_spk[r - NUM_IN];
    }
    __syncthreads();
    float acc = 0.f;
    #pragma unroll 4
    for (int u = 0; u < RPC; ++u) {
        int r = r0 + u;
        float s = spk[u];
        if (s != 0.f) {
            const float* Wrow = (r < NUM_IN) ? (W_in + (size_t)r * N)
                                             : (W_rec + (size_t)(r - NUM_IN) * N);
            acc = fmaf(s, Wrow[j], acc);
        }
    }
    partial[ic * N + j] = acc;
}

// ---------------- Stage 2: finish LIF + h = relu(combined @ pW1^T + pb1) ----
__global__ __launch_bounds__(256) void finish_mlp1(
    const float* __restrict__ partial, const float* __restrict__ potential,
    const float* __restrict__ prev_spk, const float* __restrict__ pW1,
    const float* __restrict__ pb1, float* __restrict__ out_spk,
    float* __restrict__ h) {
    __shared__ float comb[2 * N];
    __shared__ float red[256];
    int t = threadIdx.x;
    #pragma unroll
    for (int n0 = 0; n0 < N; n0 += 256) {
        int j = n0 + t;
        float tc = 0.f;
        #pragma unroll 8
        for (int ic = 0; ic < CHUNKS; ++ic) tc += partial[ic * N + j];
        float p = potential[j];
        float v = p + (-p / TAU + tc);           // DT = 1
        float s = (v >= 1.0f) ? 1.f : 0.f;
        comb[j] = prev_spk[j];
        comb[N + j] = s;
        if (blockIdx.x == 0) out_spk[j] = s;
    }
    __syncthreads();
    const float* row = pW1 + (size_t)blockIdx.x * (2 * N);
    float acc = 0.f;
    #pragma unroll
    for (int u = 0; u < 8; ++u) {
        int j = u * 256 + t;
        acc = fmaf(comb[j], row[j], acc);
    }
    red[t] = acc;
    __syncthreads();
    for (int s = 128; s > 0; s >>= 1) {
        if (t < s) red[t] += red[t + s];
        __syncthreads();
    }
    if (t == 0) h[blockIdx.x] = fmaxf(red[0] + pb1[blockIdx.x], 0.f);
}

// ---------------- Stage 3: fused policy GEMV + sigmoid + plasticity ---------
// Each 16-lane group computes TWO elements per iteration; wave covers 8
// consecutive elements -> four contiguous 1KiB nt reads per iteration (4KB),
// 2-deep software pipeline = 8KB in flight per wave; 16 iterations.
#define ITERS 16
#define ESTRIDE (8192 * 8)                       // elements advanced per iter
__global__ __launch_bounds__(256) void policy_update(
    const float* __restrict__ pW2, const float* __restrict__ pb2,
    const float* __restrict__ W_rec, const float* __restrict__ h,
    float* __restrict__ out_rec) {
    int lane = threadIdx.x & 63;
    int wave = threadIdx.x >> 6;
    int group = lane >> 4;
    int sub = lane & 15;
    int gw = blockIdx.x * 4 + wave;              // global wave id, 8192 total
    f4 hv = ((const f4*)h)[sub];                 // h[4*sub .. 4*sub+3]
    int eA = gw * 8 + group;                     // first element of pair
    const f4* prA = (const f4*)(pW2 + (size_t)eA * 64) + sub;
    const f4* grA = (const f4*)(pW2 + ((size_t)NE + eA) * 64) + sub;
    const size_t FSTRIDE = (size_t)ESTRIDE * 16; // f4 stride per iteration

    // prologue: load iteration 0  (B element = A+4 -> +64 f4s)
    f4 aA = __builtin_nontemporal_load(prA);
    f4 bA = __builtin_nontemporal_load(grA);
    f4 aB = __builtin_nontemporal_load(prA + 64);
    f4 bB = __builtin_nontemporal_load(grA + 64);
    float bpA = 0.f, bgA = 0.f, wA = 0.f, bpB = 0.f, bgB = 0.f, wB = 0.f;
    if (sub == 0) {
        bpA = pb2[eA];     bgA = pb2[NE + eA];     wA = W_rec[eA];
        bpB = pb2[eA + 4]; bgB = pb2[NE + eA + 4]; wB = W_rec[eA + 4];
    }

    for (int it = 0; it < ITERS; ++it) {
        // issue NEXT iteration's loads first (stay in flight during compute)
        f4 aAn{}, bAn{}, aBn{}, bBn{};
        float bpAn = 0.f, bgAn = 0.f, wAn = 0.f, bpBn = 0.f, bgBn = 0.f, wBn = 0.f;
        if (it + 1 < ITERS) {
            const f4* prn = prA + (size_t)(it + 1) * FSTRIDE;
            const f4* grn = grA + (size_t)(it + 1) * FSTRIDE;
            aAn = __builtin_nontemporal_load(prn);
            bAn = __builtin_nontemporal_load(grn);
            aBn = __builtin_nontemporal_load(prn + 64);
            bBn = __builtin_nontemporal_load(grn + 64);
            if (sub == 0) {
                int en = eA + (it + 1) * ESTRIDE;
                bpAn = pb2[en];     bgAn = pb2[NE + en];     wAn = W_rec[en];
                bpBn = pb2[en + 4]; bgBn = pb2[NE + en + 4]; wBn = W_rec[en + 4];
            }
        }
        // compute current iteration
        float spA = aA.x * hv.x + aA.y * hv.y + aA.z * hv.z + aA.w * hv.w;
        float sgA = bA.x * hv.x + bA.y * hv.y + bA.z * hv.z + bA.w * hv.w;
        float spB = aB.x * hv.x + aB.y * hv.y + aB.z * hv.z + aB.w * hv.w;
        float sgB = bB.x * hv.x + bB.y * hv.y + bB.z * hv.z + bB.w * hv.w;
        #pragma unroll
        for (int off = 1; off < 16; off <<= 1) {
            spA += __shfl_xor(spA, off);
            sgA += __shfl_xor(sgA, off);
            spB += __shfl_xor(spB, off);
            sgB += __shfl_xor(sgB, off);
        }
        if (sub == 0) {
            int e = eA + it * ESTRIDE;
            float sig_pA = 1.f / (1.f + __expf(-(spA + bpA)));
            float sig_gA = 1.f / (1.f + __expf(-(sgA + bgA)));
            float nwA = fmaxf(wA - LR * sig_pA + LR * sig_gA, 0.f);
            int rA = e >> 10, cA = e & (N - 1);
            if (rA == cA) nwA = 0.f;
            out_rec[e] = nwA;

            int e2 = e + 4;
            float sig_pB = 1.f / (1.f + __expf(-(spB + bpB)));
            float sig_gB = 1.f / (1.f + __expf(-(sgB + bgB)));
            float nwB = fmaxf(wB - LR * sig_pB + LR * sig_gB, 0.f);
            int rB = e2 >> 10, cB = e2 & (N - 1);
            if (rB == cB) nwB = 0.f;
            out_rec[e2] = nwB;
        }
        aA = aAn; bA = bAn; aB = aBn; bB = bBn;
        bpA = bpAn; bgA = bgAn; wA = wAn; bpB = bpBn; bgB = bgBn; wB = wBn;
    }
}

extern "C" void kernel_launch(void* const* d_in, const int* in_sizes, int n_in,
                              void* d_out, int out_size, void* d_ws, size_t ws_size,
                              hipStream_t stream) {
    const float* in_spk    = (const float*)d_in[0];
    const float* prev_spk  = (const float*)d_in[1];
    const float* potential = (const float*)d_in[2];
    const float* W_in      = (const float*)d_in[3];
    const float* W_rec     = (const float*)d_in[4];
    const float* pW1       = (const float*)d_in[5];
    const float* pb1       = (const float*)d_in[6];
    const float* pW2       = (const float*)d_in[7];
    const float* pb2       = (const float*)d_in[8];
    float* out = (float*)d_out;                  // [0,1024): spikes, then W_rec
    float* ws  = (float*)d_ws;
    float* partial = ws;                         // 64*1024 floats
    float* h       = ws + CHUNKS * N;            // 64 floats (16B-aligned)

    lif_partial<<<256, 256, 0, stream>>>(in_spk, prev_spk, W_in, W_rec, partial);
    finish_mlp1<<<64, 256, 0, stream>>>(partial, potential, prev_spk, pW1, pb1, out, h);
    policy_update<<<2048, 256, 0, stream>>>(pW2, pb2, W_rec, h, out + N);
}

// Round 7
// 113.086 us; speedup vs baseline: 1.1674x; 1.0235x over previous
//
#include <hip/hip_runtime.h>

#define N 1024
#define NUM_IN 2048
#define NE (N * N)              // 1048576 elements of W_rec
#define TAU 20.0f
#define LR 0.001f
#define CHUNKS 64
#define RPC 48                  // rows per chunk: 64*48 = 3072 reduction rows

typedef float f4 __attribute__((ext_vector_type(4)));

// ---------------- Stage 1: partial sums of total_current --------------------
// (round-3 version: wave-uniform skip branch, ~2.4 MB effective traffic)
__global__ __launch_bounds__(256) void lif_partial(
    const float* __restrict__ in_spk, const float* __restrict__ prev_spk,
    const float* __restrict__ W_in, const float* __restrict__ W_rec,
    float* __restrict__ partial) {
    __shared__ float spk[RPC];
    int jg = blockIdx.x & 3;
    int ic = blockIdx.x >> 2;
    int j = jg * 256 + threadIdx.x;
    int r0 = ic * RPC;
    if (threadIdx.x < RPC) {
        int r = r0 + threadIdx.x;
        spk[threadIdx.x] = (r < NUM_IN) ? in_spk[r] : prev_spk[r - NUM_IN];
    }
    __syncthreads();
    float acc = 0.f;
    #pragma unroll 4
    for (int u = 0; u < RPC; ++u) {
        int r = r0 + u;
        float s = spk[u];
        if (s != 0.f) {
            const float* Wrow = (r < NUM_IN) ? (W_in + (size_t)r * N)
                                             : (W_rec + (size_t)(r - NUM_IN) * N);
            acc = fmaf(s, Wrow[j], acc);
        }
    }
    partial[ic * N + j] = acc;
}

// ---------------- Stage 2: finish LIF + h = relu(combined @ pW1^T + pb1) ----
__global__ __launch_bounds__(256) void finish_mlp1(
    const float* __restrict__ partial, const float* __restrict__ potential,
    const float* __restrict__ prev_spk, const float* __restrict__ pW1,
    const float* __restrict__ pb1, float* __restrict__ out_spk,
    float* __restrict__ h) {
    __shared__ float comb[2 * N];
    __shared__ float red[256];
    int t = threadIdx.x;
    #pragma unroll
    for (int n0 = 0; n0 < N; n0 += 256) {
        int j = n0 + t;
        float tc = 0.f;
        #pragma unroll 8
        for (int ic = 0; ic < CHUNKS; ++ic) tc += partial[ic * N + j];
        float p = potential[j];
        float v = p + (-p / TAU + tc);           // DT = 1
        float s = (v >= 1.0f) ? 1.f : 0.f;
        comb[j] = prev_spk[j];
        comb[N + j] = s;
        if (blockIdx.x == 0) out_spk[j] = s;
    }
    __syncthreads();
    const float* row = pW1 + (size_t)blockIdx.x * (2 * N);
    float acc = 0.f;
    #pragma unroll
    for (int u = 0; u < 8; ++u) {
        int j = u * 256 + t;
        acc = fmaf(comb[j], row[j], acc);
    }
    red[t] = acc;
    __syncthreads();
    for (int s = 128; s > 0; s >>= 1) {
        if (t < s) red[t] += red[t + s];
        __syncthreads();
    }
    if (t == 0) h[blockIdx.x] = fmaxf(red[0] + pb1[blockIdx.x], 0.f);
}

// ---------------- Stage 3: fused policy GEMV + sigmoid + plasticity ---------
// Each 16-lane group owns FOUR CONSECUTIVE elements per iteration; a wave
// reads two 4KB contiguous spans (prune+genesis) per iteration via nt f4
// loads. Side data (pb2/W_rec) and the output are f4 vector accesses.
// 2-deep software pipeline, 8 iterations.
#define ITERS 8
#define ESTRIDE (8192 * 16)                      // elements advanced per iter
__global__ __launch_bounds__(256) void policy_update(
    const float* __restrict__ pW2, const float* __restrict__ pb2,
    const float* __restrict__ W_rec, const float* __restrict__ h,
    float* __restrict__ out_rec) {
    int lane = threadIdx.x & 63;
    int wave = threadIdx.x >> 6;
    int group = lane >> 4;
    int sub = lane & 15;
    int gw = blockIdx.x * 4 + wave;              // global wave id, 8192 total
    f4 hv = ((const f4*)h)[sub];                 // h[4*sub .. 4*sub+3]
    int e0 = gw * 16 + group * 4;                // group's 4 consecutive elems
    const f4* pr = (const f4*)pW2 + (size_t)e0 * 16 + sub;
    const f4* gr = (const f4*)pW2 + ((size_t)NE + e0) * 16 + sub;
    const size_t FSTR = (size_t)ESTRIDE * 16;    // f4 stride per iteration

    // prologue: iteration 0 loads (element m's row is +m*16 f4s)
    f4 pA[4], gA[4];
    #pragma unroll
    for (int m = 0; m < 4; ++m) {
        pA[m] = __builtin_nontemporal_load(pr + m * 16);
        gA[m] = __builtin_nontemporal_load(gr + m * 16);
    }
    f4 bp{}, bg{}, wv{};
    if (sub == 0) {
        bp = *(const f4*)(pb2 + e0);
        bg = *(const f4*)(pb2 + NE + e0);
        wv = *(const f4*)(W_rec + e0);
    }

    for (int it = 0; it < ITERS; ++it) {
        // issue NEXT iteration's loads first (stay in flight during compute)
        f4 pN[4] = {}, gN[4] = {};
        f4 bpn{}, bgn{}, wvn{};
        if (it + 1 < ITERS) {
            const f4* prn = pr + (size_t)(it + 1) * FSTR;
            const f4* grn = gr + (size_t)(it + 1) * FSTR;
            #pragma unroll
            for (int m = 0; m < 4; ++m) {
                pN[m] = __builtin_nontemporal_load(prn + m * 16);
                gN[m] = __builtin_nontemporal_load(grn + m * 16);
            }
            if (sub == 0) {
                int en = e0 + (it + 1) * ESTRIDE;
                bpn = *(const f4*)(pb2 + en);
                bgn = *(const f4*)(pb2 + NE + en);
                wvn = *(const f4*)(W_rec + en);
            }
        }
        // compute current iteration: 8 dot-fragments, 8 parallel reductions
        float sp[4], sg[4];
        #pragma unroll
        for (int m = 0; m < 4; ++m) {
            sp[m] = pA[m].x * hv.x + pA[m].y * hv.y + pA[m].z * hv.z + pA[m].w * hv.w;
            sg[m] = gA[m].x * hv.x + gA[m].y * hv.y + gA[m].z * hv.z + gA[m].w * hv.w;
        }
        #pragma unroll
        for (int off = 1; off < 16; off <<= 1) {
            #pragma unroll
            for (int m = 0; m < 4; ++m) {
                sp[m] += __shfl_xor(sp[m], off);
                sg[m] += __shfl_xor(sg[m], off);
            }
        }
        if (sub == 0) {
            int e = e0 + it * ESTRIDE;
            f4 res;
            #pragma unroll
            for (int m = 0; m < 4; ++m) {
                float sig_p = 1.f / (1.f + __expf(-(sp[m] + bp[m])));
                float sig_g = 1.f / (1.f + __expf(-(sg[m] + bg[m])));
                float nw = fmaxf(wv[m] - LR * sig_p + LR * sig_g, 0.f);
                int em = e + m;
                int r = em >> 10, c = em & (N - 1);
                res[m] = (r == c) ? 0.f : nw;
            }
            *(f4*)(out_rec + e) = res;
        }
        #pragma unroll
        for (int m = 0; m < 4; ++m) { pA[m] = pN[m]; gA[m] = gN[m]; }
        bp = bpn; bg = bgn; wv = wvn;
    }
}

extern "C" void kernel_launch(void* const* d_in, const int* in_sizes, int n_in,
                              void* d_out, int out_size, void* d_ws, size_t ws_size,
                              hipStream_t stream) {
    const float* in_spk    = (const float*)d_in[0];
    const float* prev_spk  = (const float*)d_in[1];
    const float* potential = (const float*)d_in[2];
    const float* W_in      = (const float*)d_in[3];
    const float* W_rec     = (const float*)d_in[4];
    const float* pW1       = (const float*)d_in[5];
    const float* pb1       = (const float*)d_in[6];
    const float* pW2       = (const float*)d_in[7];
    const float* pb2       = (const float*)d_in[8];
    float* out = (float*)d_out;                  // [0,1024): spikes, then W_rec
    float* ws  = (float*)d_ws;
    float* partial = ws;                         // 64*1024 floats
    float* h       = ws + CHUNKS * N;            // 64 floats (16B-aligned)

    lif_partial<<<256, 256, 0, stream>>>(in_spk, prev_spk, W_in, W_rec, partial);
    finish_mlp1<<<64, 256, 0, stream>>>(partial, potential, prev_spk, pW1, pb1, out, h);
    policy_update<<<2048, 256, 0, stream>>>(pW2, pb2, W_rec, h, out + N);
}

// Round 8
// 112.502 us; speedup vs baseline: 1.1734x; 1.0052x over previous
//
#include <hip/hip_runtime.h>

#define N 1024
#define NUM_IN 2048
#define NE (N * N)              // 1048576 elements of W_rec
#define TAU 20.0f
#define LR 0.001f
#define CHUNKS 64
#define RPC 48                  // rows per chunk: 64*48 = 3072 reduction rows

typedef float f4 __attribute__((ext_vector_type(4)));

// ---------------- Stage 1: partial sums of total_current --------------------
// (round-3 version: wave-uniform skip branch, ~2.4 MB effective traffic)
__global__ __launch_bounds__(256) void lif_partial(
    const float* __restrict__ in_spk, const float* __restrict__ prev_spk,
    const float* __restrict__ W_in, const float* __restrict__ W_rec,
    float* __restrict__ partial) {
    __shared__ float spk[RPC];
    int jg = blockIdx.x & 3;
    int ic = blockIdx.x >> 2;
    int j = jg * 256 + threadIdx.x;
    int r0 = ic * RPC;
    if (threadIdx.x < RPC) {
        int r = r0 + threadIdx.x;
        spk[threadIdx.x] = (r < NUM_IN) ? in_spk[r] : prev_spk[r - NUM_IN];
    }
    __syncthreads();
    float acc = 0.f;
    #pragma unroll 4
    for (int u = 0; u < RPC; ++u) {
        int r = r0 + u;
        float s = spk[u];
        if (s != 0.f) {
            const float* Wrow = (r < NUM_IN) ? (W_in + (size_t)r * N)
                                             : (W_rec + (size_t)(r - NUM_IN) * N);
            acc = fmaf(s, Wrow[j], acc);
        }
    }
    partial[ic * N + j] = acc;
}

// ---------------- Stage 2: finish LIF + h = relu(combined @ pW1^T + pb1) ----
__global__ __launch_bounds__(256) void finish_mlp1(
    const float* __restrict__ partial, const float* __restrict__ potential,
    const float* __restrict__ prev_spk, const float* __restrict__ pW1,
    const float* __restrict__ pb1, float* __restrict__ out_spk,
    float* __restrict__ h) {
    __shared__ float comb[2 * N];
    __shared__ float red[256];
    int t = threadIdx.x;
    #pragma unroll
    for (int n0 = 0; n0 < N; n0 += 256) {
        int j = n0 + t;
        float tc = 0.f;
        #pragma unroll 8
        for (int ic = 0; ic < CHUNKS; ++ic) tc += partial[ic * N + j];
        float p = potential[j];
        float v = p + (-p / TAU + tc);           // DT = 1
        float s = (v >= 1.0f) ? 1.f : 0.f;
        comb[j] = prev_spk[j];
        comb[N + j] = s;
        if (blockIdx.x == 0) out_spk[j] = s;
    }
    __syncthreads();
    const float* row = pW1 + (size_t)blockIdx.x * (2 * N);
    float acc = 0.f;
    #pragma unroll
    for (int u = 0; u < 8; ++u) {
        int j = u * 256 + t;
        acc = fmaf(comb[j], row[j], acc);
    }
    red[t] = acc;
    __syncthreads();
    for (int s = 128; s > 0; s >>= 1) {
        if (t < s) red[t] += red[t + s];
        __syncthreads();
    }
    if (t == 0) h[blockIdx.x] = fmaxf(red[0] + pb1[blockIdx.x], 0.f);
}

// ---------------- Stage 3: fused policy GEMV + sigmoid + plasticity ---------
// Identical structure to round 6 (4 consecutive elements per 16-lane group,
// 8KB/wave/iter, 2-deep pipeline, 8 iterations) EXCEPT load policy:
// prune-stream loads for iterations 0..5 (elements e < 768K = 192 MiB) are
// PLAIN (temporal -> MALL-resident across graph replays); all other pW2
// loads stay nontemporal (evict-first) so they can't thrash that slice.
#define ITERS 8
#define RESIT 6                                  // iterations with resident prune slice
#define ESTRIDE (8192 * 16)                      // elements advanced per iter
__global__ __launch_bounds__(256) void policy_update(
    const float* __restrict__ pW2, const float* __restrict__ pb2,
    const float* __restrict__ W_rec, const float* __restrict__ h,
    float* __restrict__ out_rec) {
    int lane = threadIdx.x & 63;
    int wave = threadIdx.x >> 6;
    int group = lane >> 4;
    int sub = lane & 15;
    int gw = blockIdx.x * 4 + wave;              // global wave id, 8192 total
    f4 hv = ((const f4*)h)[sub];                 // h[4*sub .. 4*sub+3]
    int e0 = gw * 16 + group * 4;                // group's 4 consecutive elems
    const f4* pr = (const f4*)pW2 + (size_t)e0 * 16 + sub;
    const f4* gr = (const f4*)pW2 + ((size_t)NE + e0) * 16 + sub;
    const size_t FSTR = (size_t)ESTRIDE * 16;    // f4 stride per iteration

    // prologue: iteration 0 loads (element m's row is +m*16 f4s)
    f4 pA[4], gA[4];
    #pragma unroll
    for (int m = 0; m < 4; ++m) {
        pA[m] = pr[m * 16];                      // it=0 < RESIT: plain load
        gA[m] = __builtin_nontemporal_load(gr + m * 16);
    }
    f4 bp{}, bg{}, wv{};
    if (sub == 0) {
        bp = *(const f4*)(pb2 + e0);
        bg = *(const f4*)(pb2 + NE + e0);
        wv = *(const f4*)(W_rec + e0);
    }

    for (int it = 0; it < ITERS; ++it) {
        // issue NEXT iteration's loads first (stay in flight during compute)
        f4 pN[4] = {}, gN[4] = {};
        f4 bpn{}, bgn{}, wvn{};
        if (it + 1 < ITERS) {
            const f4* prn = pr + (size_t)(it + 1) * FSTR;
            const f4* grn = gr + (size_t)(it + 1) * FSTR;
            if (it + 1 < RESIT) {                // wave-uniform scalar branch
                #pragma unroll
                for (int m = 0; m < 4; ++m) {
                    pN[m] = prn[m * 16];         // temporal: MALL-resident slice
                    gN[m] = __builtin_nontemporal_load(grn + m * 16);
                }
            } else {
                #pragma unroll
                for (int m = 0; m < 4; ++m) {
                    pN[m] = __builtin_nontemporal_load(prn + m * 16);
                    gN[m] = __builtin_nontemporal_load(grn + m * 16);
                }
            }
            if (sub == 0) {
                int en = e0 + (it + 1) * ESTRIDE;
                bpn = *(const f4*)(pb2 + en);
                bgn = *(const f4*)(pb2 + NE + en);
                wvn = *(const f4*)(W_rec + en);
            }
        }
        // compute current iteration: 8 dot-fragments, 8 parallel reductions
        float sp[4], sg[4];
        #pragma unroll
        for (int m = 0; m < 4; ++m) {
            sp[m] = pA[m].x * hv.x + pA[m].y * hv.y + pA[m].z * hv.z + pA[m].w * hv.w;
            sg[m] = gA[m].x * hv.x + gA[m].y * hv.y + gA[m].z * hv.z + gA[m].w * hv.w;
        }
        #pragma unroll
        for (int off = 1; off < 16; off <<= 1) {
            #pragma unroll
            for (int m = 0; m < 4; ++m) {
                sp[m] += __shfl_xor(sp[m], off);
                sg[m] += __shfl_xor(sg[m], off);
            }
        }
        if (sub == 0) {
            int e = e0 + it * ESTRIDE;
            f4 res;
            #pragma unroll
            for (int m = 0; m < 4; ++m) {
                float sig_p = 1.f / (1.f + __expf(-(sp[m] + bp[m])));
                float sig_g = 1.f / (1.f + __expf(-(sg[m] + bg[m])));
                float nw = fmaxf(wv[m] - LR * sig_p + LR * sig_g, 0.f);
                int em = e + m;
                int r = em >> 10, c = em & (N - 1);
                res[m] = (r == c) ? 0.f : nw;
            }
            *(f4*)(out_rec + e) = res;
        }
        #pragma unroll
        for (int m = 0; m < 4; ++m) { pA[m] = pN[m]; gA[m] = gN[m]; }
        bp = bpn; bg = bgn; wv = wvn;
    }
}

extern "C" void kernel_launch(void* const* d_in, const int* in_sizes, int n_in,
                              void* d_out, int out_size, void* d_ws, size_t ws_size,
                              hipStream_t stream) {
    const float* in_spk    = (const float*)d_in[0];
    const float* prev_spk  = (const float*)d_in[1];
    const float* potential = (const float*)d_in[2];
    const float* W_in      = (const float*)d_in[3];
    const float* W_rec     = (const float*)d_in[4];
    const float* pW1       = (const float*)d_in[5];
    const float* pb1       = (const float*)d_in[6];
    const float* pW2       = (const float*)d_in[7];
    const float* pb2       = (const float*)d_in[8];
    float* out = (float*)d_out;                  // [0,1024): spikes, then W_rec
    float* ws  = (float*)d_ws;
    float* partial = ws;                         // 64*1024 floats
    float* h       = ws + CHUNKS * N;            // 64 floats (16B-aligned)

    lif_partial<<<256, 256, 0, stream>>>(in_spk, prev_spk, W_in, W_rec, partial);
    finish_mlp1<<<64, 256, 0, stream>>>(partial, potential, prev_spk, pW1, pb1, out, h);
    policy_update<<<2048, 256, 0, stream>>>(pW2, pb2, W_rec, h, out + N);
}